// Round 6
// baseline (799.850 us; speedup 1.0000x reference)
//
#include <hip/hip_runtime.h>

#define NN 100000
#define DD 128
#define EE 1600000
#define BN_EPS 1e-5f

__device__ __forceinline__ unsigned short bf16r(float f) {
    unsigned u = __float_as_uint(f);
    u += 0x7FFF + ((u >> 16) & 1);   // round-to-nearest-even
    return (unsigned short)(u >> 16);
}
__device__ __forceinline__ float bf2f(unsigned short h) {
    return __uint_as_float((unsigned)h << 16);
}
__device__ __forceinline__ float4 up4(ushort4 u) {
    float4 f;
    f.x = bf2f(u.x); f.y = bf2f(u.y); f.z = bf2f(u.z); f.w = bf2f(u.w);
    return f;
}

// ---------------- degree histogram (int4 edge loads) ----------------
__global__ void deg4_kernel(const int4* __restrict__ src4, const int4* __restrict__ dst4,
                            int* __restrict__ outdeg, int* __restrict__ indeg) {
    int i = blockIdx.x * blockDim.x + threadIdx.x;
    if (i < EE / 4) {
        int4 s = src4[i];
        int4 d = dst4[i];
        atomicAdd(&outdeg[s.x], 1); atomicAdd(&outdeg[s.y], 1);
        atomicAdd(&outdeg[s.z], 1); atomicAdd(&outdeg[s.w], 1);
        atomicAdd(&indeg[d.x], 1); atomicAdd(&indeg[d.y], 1);
        atomicAdd(&indeg[d.z], 1); atomicAdd(&indeg[d.w], 1);
    }
}

// ---------------- scan phase 1: per-block inclusive scan of indeg ----------------
__global__ __launch_bounds__(1024) void scan1_kernel(const int* __restrict__ indeg,
                                                     int* __restrict__ partial,
                                                     int* __restrict__ blocksum) {
    __shared__ int s[1024];
    int t = threadIdx.x;
    int idx = blockIdx.x * 1024 + t;
    int v = (idx < NN) ? indeg[idx] : 0;
    s[t] = v;
    __syncthreads();
    for (int off = 1; off < 1024; off <<= 1) {
        int x = (t >= off) ? s[t - off] : 0;
        __syncthreads();
        s[t] += x;
        __syncthreads();
    }
    if (idx < NN) partial[idx] = s[t] - v;  // exclusive within block
    if (t == 1023) blocksum[blockIdx.x] = s[t];
}

// ---------------- scan phase 2: scan the 98 block sums ----------------
__global__ void scan2_kernel(const int* __restrict__ blocksum, int* __restrict__ blockofs) {
    __shared__ int s[128];
    int t = threadIdx.x;
    int v = (t < 98) ? blocksum[t] : 0;
    s[t] = v;
    __syncthreads();
    for (int off = 1; off < 128; off <<= 1) {
        int x = (t >= off) ? s[t - off] : 0;
        __syncthreads();
        s[t] += x;
        __syncthreads();
    }
    if (t < 98) blockofs[t] = s[t] - v;
}

// ---------------- scan phase 3 + norms ----------------
__global__ void scan3_kernel(const int* __restrict__ partial, const int* __restrict__ blockofs,
                             const int* __restrict__ outdeg, const int* __restrict__ indeg,
                             int* __restrict__ row_ofs, int* __restrict__ cursor,
                             float* __restrict__ ns, float* __restrict__ nd) {
    int i = blockIdx.x * blockDim.x + threadIdx.x;
    if (i < NN) {
        int ro = partial[i] + blockofs[i >> 10];
        row_ofs[i] = ro;
        cursor[i] = ro;
        ns[i] = rsqrtf(fmaxf((float)outdeg[i], 1.0f));
        nd[i] = rsqrtf(fmaxf((float)indeg[i], 1.0f));
        if (i == 0) row_ofs[NN] = EE;
    }
}

// ---------------- feats -> bf16 pre-scaled by ns ----------------
__global__ void cvt_kernel(const float4* __restrict__ feats4, const float* __restrict__ ns,
                           ushort4* __restrict__ fb4) {
    int i = blockIdx.x * blockDim.x + threadIdx.x;  // NN*32 = 3.2M
    if (i < NN * 32) {
        float s = ns[i >> 5];
        float4 v = feats4[i];
        ushort4 h;
        h.x = bf16r(v.x * s);
        h.y = bf16r(v.y * s);
        h.z = bf16r(v.z * s);
        h.w = bf16r(v.w * s);
        fb4[i] = h;
    }
}

// ---------------- CSR fill (int4 edge loads) ----------------
__global__ void fill4_kernel(const int4* __restrict__ src4, const int4* __restrict__ dst4,
                             int* __restrict__ cursor, int* __restrict__ e_src) {
    int i = blockIdx.x * blockDim.x + threadIdx.x;
    if (i < EE / 4) {
        int4 s = src4[i];
        int4 d = dst4[i];
        e_src[atomicAdd(&cursor[d.x], 1)] = s.x;
        e_src[atomicAdd(&cursor[d.y], 1)] = s.y;
        e_src[atomicAdd(&cursor[d.z], 1)] = s.z;
        e_src[atomicAdd(&cursor[d.w], 1)] = s.w;
    }
}

// ---------------- fused gather + dual GEMM + bias/relu/add + BN colsum ----------------
// block = 256 threads, 32 nodes/block, 3125 blocks. bf16 LDS tiles -> 16KB -> 8 blocks/CU
__global__ __launch_bounds__(256, 8) void gg_kernel(
    const float* __restrict__ feats, const ushort4* __restrict__ fb4,
    const float* __restrict__ nd,
    const int* __restrict__ row_ofs, const int* __restrict__ e_src,
    const float* __restrict__ W, const float* __restrict__ b,
    const float* __restrict__ Wr, const float* __restrict__ br,
    float* __restrict__ y, float* __restrict__ colsum, float* __restrict__ colsumsq) {
    __shared__ unsigned short AsH[32 * 128];  // 8KB (bf16)
    __shared__ unsigned short FsH[32 * 128];  // 8KB (bf16)
    const int block_row = blockIdx.x * 32;
    const int tid = threadIdx.x;
    const int lane = tid & 31;
    const int grp = tid >> 5;  // 0..7
    const float4* feats4 = (const float4*)feats;

    // stage feats rows as bf16 for the residual GEMM
    for (int i = tid; i < 1024; i += 256) {
        int r = i >> 5;
        int c4 = i & 31;
        float4 v = feats4[(size_t)(block_row + r) * 32 + c4];
        ushort4 h;
        h.x = bf16r(v.x); h.y = bf16r(v.y); h.z = bf16r(v.z); h.w = bf16r(v.w);
        ((ushort4*)(FsH + r * 128))[c4] = h;
    }

    // gather-aggregate: each 32-lane group does 4 nodes; 4 independent accumulators
    for (int n = 0; n < 4; ++n) {
        int nl = grp * 4 + n;
        int node = block_row + nl;
        int beg = row_ofs[node];
        int end = row_ofs[node + 1];
        float4 a0 = {0.f, 0.f, 0.f, 0.f};
        float4 a1 = {0.f, 0.f, 0.f, 0.f};
        float4 a2 = {0.f, 0.f, 0.f, 0.f};
        float4 a3 = {0.f, 0.f, 0.f, 0.f};
        int e = beg;
        for (; e + 3 < end; e += 4) {
            int s0 = e_src[e], s1 = e_src[e + 1], s2 = e_src[e + 2], s3 = e_src[e + 3];
            float4 v0 = up4(fb4[s0 * 32 + lane]);
            float4 v1 = up4(fb4[s1 * 32 + lane]);
            float4 v2 = up4(fb4[s2 * 32 + lane]);
            float4 v3 = up4(fb4[s3 * 32 + lane]);
            a0.x += v0.x; a0.y += v0.y; a0.z += v0.z; a0.w += v0.w;
            a1.x += v1.x; a1.y += v1.y; a1.z += v1.z; a1.w += v1.w;
            a2.x += v2.x; a2.y += v2.y; a2.z += v2.z; a2.w += v2.w;
            a3.x += v3.x; a3.y += v3.y; a3.z += v3.z; a3.w += v3.w;
        }
        for (; e < end; ++e) {
            float4 v0 = up4(fb4[e_src[e] * 32 + lane]);
            a0.x += v0.x; a0.y += v0.y; a0.z += v0.z; a0.w += v0.w;
        }
        float snd = nd[node];
        ushort4 h;
        h.x = bf16r((a0.x + a1.x + a2.x + a3.x) * snd);
        h.y = bf16r((a0.y + a1.y + a2.y + a3.y) * snd);
        h.z = bf16r((a0.z + a1.z + a2.z + a3.z) * snd);
        h.w = bf16r((a0.w + a1.w + a2.w + a3.w) * snd);
        ((ushort4*)(AsH + nl * 128))[lane] = h;
    }
    __syncthreads();

    const int rr = tid >> 5;  // rows rr*4 .. rr*4+3
    const int cc = tid & 31;  // cols cc*4 .. cc*4+3

    float accC[4][4] = {{0.f}};
    float accR[4][4] = {{0.f}};

    for (int k4 = 0; k4 < 32; ++k4) {
        float4 a4[4], f4[4];
#pragma unroll
        for (int r = 0; r < 4; ++r) {
            a4[r] = up4(((const ushort4*)(AsH + (rr * 4 + r) * 128))[k4]);
            f4[r] = up4(((const ushort4*)(FsH + (rr * 4 + r) * 128))[k4]);
        }
#pragma unroll
        for (int kk = 0; kk < 4; ++kk) {
            int k = k4 * 4 + kk;
            float4 wv = ((const float4*)W)[k * 32 + cc];
            float4 wrv = ((const float4*)Wr)[k * 32 + cc];
#pragma unroll
            for (int r = 0; r < 4; ++r) {
                float a = (kk == 0) ? a4[r].x : (kk == 1) ? a4[r].y : (kk == 2) ? a4[r].z : a4[r].w;
                float f = (kk == 0) ? f4[r].x : (kk == 1) ? f4[r].y : (kk == 2) ? f4[r].z : f4[r].w;
                accC[r][0] += a * wv.x;  accC[r][1] += a * wv.y;
                accC[r][2] += a * wv.z;  accC[r][3] += a * wv.w;
                accR[r][0] += f * wrv.x; accR[r][1] += f * wrv.y;
                accR[r][2] += f * wrv.z; accR[r][3] += f * wrv.w;
            }
        }
    }

    float4 bv = ((const float4*)b)[cc];
    float4 brv = ((const float4*)br)[cc];
    float csum[4] = {0.f, 0.f, 0.f, 0.f};
    float csq[4] = {0.f, 0.f, 0.f, 0.f};
#pragma unroll
    for (int r = 0; r < 4; ++r) {
        int row = block_row + rr * 4 + r;
        float4 o;
        o.x = fmaxf(accC[r][0] + bv.x, 0.f) + fmaxf(accR[r][0] + brv.x, 0.f);
        o.y = fmaxf(accC[r][1] + bv.y, 0.f) + fmaxf(accR[r][1] + brv.y, 0.f);
        o.z = fmaxf(accC[r][2] + bv.z, 0.f) + fmaxf(accR[r][2] + brv.z, 0.f);
        o.w = fmaxf(accC[r][3] + bv.w, 0.f) + fmaxf(accR[r][3] + brv.w, 0.f);
        ((float4*)y)[(size_t)row * 32 + cc] = o;
        csum[0] += o.x; csum[1] += o.y; csum[2] += o.z; csum[3] += o.w;
        csq[0] += o.x * o.x; csq[1] += o.y * o.y; csq[2] += o.z * o.z; csq[3] += o.w * o.w;
    }

    // block-level column reduction: reuse AsH (sum) and FsH (sumsq) as float arrays
    __syncthreads();
    float* Ssum = (float*)AsH;  // 2048 floats avail, need 1024
    float* Ssq = (float*)FsH;
#pragma unroll
    for (int j = 0; j < 4; ++j) {
        Ssum[rr * 128 + cc * 4 + j] = csum[j];
        Ssq[rr * 128 + cc * 4 + j] = csq[j];
    }
    __syncthreads();
    if (tid < 128) {
        float s = 0.f, q = 0.f;
#pragma unroll
        for (int g = 0; g < 8; ++g) {
            s += Ssum[g * 128 + tid];
            q += Ssq[g * 128 + tid];
        }
        atomicAdd(&colsum[tid], s);
        atomicAdd(&colsumsq[tid], q);
    }
}

// ---------------- BN stats finalize ----------------
__global__ void stats_kernel(const float* __restrict__ colsum, const float* __restrict__ colsumsq,
                             const float* __restrict__ gamma, const float* __restrict__ beta,
                             float* __restrict__ scale, float* __restrict__ shift) {
    int j = threadIdx.x;
    if (j < DD) {
        float inv_n = 1.0f / (float)NN;
        float mean = colsum[j] * inv_n;
        float var = colsumsq[j] * inv_n - mean * mean;
        float sc = gamma[j] * rsqrtf(var + BN_EPS);
        scale[j] = sc;
        shift[j] = beta[j] - mean * sc;
    }
}

// ---------------- BN apply (in place on d_out) ----------------
__global__ void apply_kernel(float4* __restrict__ y4,
                             const float* __restrict__ scale, const float* __restrict__ shift,
                             int total4) {
    int i = blockIdx.x * blockDim.x + threadIdx.x;
    if (i < total4) {
        int c4 = i & 31;
        float4 v = y4[i];
        float4 sc = ((const float4*)scale)[c4];
        float4 sh = ((const float4*)shift)[c4];
        v.x = v.x * sc.x + sh.x;
        v.y = v.y * sc.y + sh.y;
        v.z = v.z * sc.z + sh.z;
        v.w = v.w * sc.w + sh.w;
        y4[i] = v;
    }
}

extern "C" void kernel_launch(void* const* d_in, const int* in_sizes, int n_in,
                              void* d_out, int out_size, void* d_ws, size_t ws_size,
                              hipStream_t stream) {
    const float* feats = (const float*)d_in[0];
    const int* src = (const int*)d_in[1];
    const int* dst = (const int*)d_in[2];
    const float* W = (const float*)d_in[3];
    const float* b = (const float*)d_in[4];
    const float* Wr = (const float*)d_in[5];
    const float* br = (const float*)d_in[6];
    const float* gamma = (const float*)d_in[7];
    const float* beta = (const float*)d_in[8];
    float* y = (float*)d_out;

    // workspace carve
    char* ws = (char*)d_ws;
    ushort4* fb4 = (ushort4*)ws;                              // NN*32 ushort4 = 25.6 MB
    int* outdeg = (int*)(ws + (size_t)NN * 32 * 8);           // NN
    int* indeg = outdeg + NN;                                 // NN
    float* ns = (float*)(indeg + NN);                         // NN
    float* nd = ns + NN;                                      // NN
    int* row_ofs = (int*)(nd + NN);                           // NN+1
    int* cursor = row_ofs + NN + 1;                           // NN
    int* partial = cursor + NN;                               // NN
    int* blocksum = partial + NN;                             // 98
    int* blockofs = blocksum + 128;                           // 98
    int* e_src = blockofs + 128;                              // EE
    float* colsum = (float*)(e_src + EE);                     // 128
    float* colsumsq = colsum + DD;                            // 128
    float* scale = colsumsq + DD;                             // 128
    float* shift = scale + DD;                                // 128

    hipMemsetAsync(outdeg, 0, 2 * (size_t)NN * sizeof(int), stream);
    hipMemsetAsync(colsum, 0, 2 * (size_t)DD * sizeof(float), stream);

    deg4_kernel<<<(EE / 4 + 255) / 256, 256, 0, stream>>>((const int4*)src, (const int4*)dst,
                                                          outdeg, indeg);
    scan1_kernel<<<98, 1024, 0, stream>>>(indeg, partial, blocksum);
    scan2_kernel<<<1, 128, 0, stream>>>(blocksum, blockofs);
    scan3_kernel<<<(NN + 255) / 256, 256, 0, stream>>>(partial, blockofs, outdeg, indeg,
                                                       row_ofs, cursor, ns, nd);
    cvt_kernel<<<(NN * 32 + 255) / 256, 256, 0, stream>>>((const float4*)feats, ns, fb4);
    fill4_kernel<<<(EE / 4 + 255) / 256, 256, 0, stream>>>((const int4*)src, (const int4*)dst,
                                                           cursor, e_src);
    gg_kernel<<<NN / 32, 256, 0, stream>>>(feats, fb4, nd, row_ofs, e_src,
                                           W, b, Wr, br, y, colsum, colsumsq);
    stats_kernel<<<1, 128, 0, stream>>>(colsum, colsumsq, gamma, beta, scale, shift);
    {
        int total4 = NN * DD / 4;
        apply_kernel<<<(total4 + 255) / 256, 256, 0, stream>>>((float4*)y, scale, shift, total4);
    }
}

// Round 7
// 686.960 us; speedup vs baseline: 1.1643x; 1.1643x over previous
//
#include <hip/hip_runtime.h>

#define NN 100000
#define DD 128
#define EE 1600000
#define BN_EPS 1e-5f

__device__ __forceinline__ unsigned short bf16r(float f) {
    unsigned u = __float_as_uint(f);
    u += 0x7FFF + ((u >> 16) & 1);   // round-to-nearest-even
    return (unsigned short)(u >> 16);
}
__device__ __forceinline__ float bf2f(unsigned short h) {
    return __uint_as_float((unsigned)h << 16);
}
__device__ __forceinline__ float4 up4(ushort4 u) {
    float4 f;
    f.x = bf2f(u.x); f.y = bf2f(u.y); f.z = bf2f(u.z); f.w = bf2f(u.w);
    return f;
}

// ---------------- degree histogram (int4 edge loads) ----------------
__global__ void deg4_kernel(const int4* __restrict__ src4, const int4* __restrict__ dst4,
                            int* __restrict__ outdeg, int* __restrict__ indeg) {
    int i = blockIdx.x * blockDim.x + threadIdx.x;
    if (i < EE / 4) {
        int4 s = src4[i];
        int4 d = dst4[i];
        atomicAdd(&outdeg[s.x], 1); atomicAdd(&outdeg[s.y], 1);
        atomicAdd(&outdeg[s.z], 1); atomicAdd(&outdeg[s.w], 1);
        atomicAdd(&indeg[d.x], 1); atomicAdd(&indeg[d.y], 1);
        atomicAdd(&indeg[d.z], 1); atomicAdd(&indeg[d.w], 1);
    }
}

// ---------------- scan phase 1: per-block inclusive scan of indeg ----------------
__global__ __launch_bounds__(1024) void scan1_kernel(const int* __restrict__ indeg,
                                                     int* __restrict__ partial,
                                                     int* __restrict__ blocksum) {
    __shared__ int s[1024];
    int t = threadIdx.x;
    int idx = blockIdx.x * 1024 + t;
    int v = (idx < NN) ? indeg[idx] : 0;
    s[t] = v;
    __syncthreads();
    for (int off = 1; off < 1024; off <<= 1) {
        int x = (t >= off) ? s[t - off] : 0;
        __syncthreads();
        s[t] += x;
        __syncthreads();
    }
    if (idx < NN) partial[idx] = s[t] - v;  // exclusive within block
    if (t == 1023) blocksum[blockIdx.x] = s[t];
}

// ---------------- scan phase 2: scan the 98 block sums ----------------
__global__ void scan2_kernel(const int* __restrict__ blocksum, int* __restrict__ blockofs) {
    __shared__ int s[128];
    int t = threadIdx.x;
    int v = (t < 98) ? blocksum[t] : 0;
    s[t] = v;
    __syncthreads();
    for (int off = 1; off < 128; off <<= 1) {
        int x = (t >= off) ? s[t - off] : 0;
        __syncthreads();
        s[t] += x;
        __syncthreads();
    }
    if (t < 98) blockofs[t] = s[t] - v;
}

// ---------------- scan phase 3 + norms ----------------
__global__ void scan3_kernel(const int* __restrict__ partial, const int* __restrict__ blockofs,
                             const int* __restrict__ outdeg, const int* __restrict__ indeg,
                             int* __restrict__ row_ofs, int* __restrict__ cursor,
                             float* __restrict__ ns, float* __restrict__ nd) {
    int i = blockIdx.x * blockDim.x + threadIdx.x;
    if (i < NN) {
        int ro = partial[i] + blockofs[i >> 10];
        row_ofs[i] = ro;
        cursor[i] = ro;
        ns[i] = rsqrtf(fmaxf((float)outdeg[i], 1.0f));
        nd[i] = rsqrtf(fmaxf((float)indeg[i], 1.0f));
        if (i == 0) row_ofs[NN] = EE;
    }
}

// ---------------- feats -> bf16 pre-scaled by ns ----------------
__global__ void cvt_kernel(const float4* __restrict__ feats4, const float* __restrict__ ns,
                           ushort4* __restrict__ fb4) {
    int i = blockIdx.x * blockDim.x + threadIdx.x;  // NN*32 = 3.2M
    if (i < NN * 32) {
        float s = ns[i >> 5];
        float4 v = feats4[i];
        ushort4 h;
        h.x = bf16r(v.x * s);
        h.y = bf16r(v.y * s);
        h.z = bf16r(v.z * s);
        h.w = bf16r(v.w * s);
        fb4[i] = h;
    }
}

// ---------------- CSR fill (int4 edge loads) ----------------
__global__ void fill4_kernel(const int4* __restrict__ src4, const int4* __restrict__ dst4,
                             int* __restrict__ cursor, int* __restrict__ e_src) {
    int i = blockIdx.x * blockDim.x + threadIdx.x;
    if (i < EE / 4) {
        int4 s = src4[i];
        int4 d = dst4[i];
        e_src[atomicAdd(&cursor[d.x], 1)] = s.x;
        e_src[atomicAdd(&cursor[d.y], 1)] = s.y;
        e_src[atomicAdd(&cursor[d.z], 1)] = s.z;
        e_src[atomicAdd(&cursor[d.w], 1)] = s.w;
    }
}

// ---------------- fused gather + dual GEMM + bias/relu/add + BN colsum ----------------
// block = 256 threads, 32 nodes/block, 3125 blocks. bf16 LDS tiles = 16KB.
// NOTE: no min-waves clamp — (256,8) forced VGPR=32 and spilled to scratch
// (WRITE_SIZE 53->315MB, gg 230->417us). Let the allocator pick (~56-64 VGPR).
__global__ __launch_bounds__(256) void gg_kernel(
    const float* __restrict__ feats, const ushort4* __restrict__ fb4,
    const float* __restrict__ nd,
    const int* __restrict__ row_ofs, const int* __restrict__ e_src,
    const float* __restrict__ W, const float* __restrict__ b,
    const float* __restrict__ Wr, const float* __restrict__ br,
    float* __restrict__ y, float* __restrict__ colsum, float* __restrict__ colsumsq) {
    __shared__ unsigned short AsH[32 * 128];  // 8KB (bf16)
    __shared__ unsigned short FsH[32 * 128];  // 8KB (bf16)
    const int block_row = blockIdx.x * 32;
    const int tid = threadIdx.x;
    const int lane = tid & 31;
    const int grp = tid >> 5;  // 0..7
    const float4* feats4 = (const float4*)feats;

    // stage feats rows as bf16 for the residual GEMM
    for (int i = tid; i < 1024; i += 256) {
        int r = i >> 5;
        int c4 = i & 31;
        float4 v = feats4[(size_t)(block_row + r) * 32 + c4];
        ushort4 h;
        h.x = bf16r(v.x); h.y = bf16r(v.y); h.z = bf16r(v.z); h.w = bf16r(v.w);
        ((ushort4*)(FsH + r * 128))[c4] = h;
    }

    // gather-aggregate: each 32-lane group does 4 nodes; 4 independent accumulators
    for (int n = 0; n < 4; ++n) {
        int nl = grp * 4 + n;
        int node = block_row + nl;
        int beg = row_ofs[node];
        int end = row_ofs[node + 1];
        float4 a0 = {0.f, 0.f, 0.f, 0.f};
        float4 a1 = {0.f, 0.f, 0.f, 0.f};
        float4 a2 = {0.f, 0.f, 0.f, 0.f};
        float4 a3 = {0.f, 0.f, 0.f, 0.f};
        int e = beg;
        for (; e + 3 < end; e += 4) {
            int s0 = e_src[e], s1 = e_src[e + 1], s2 = e_src[e + 2], s3 = e_src[e + 3];
            float4 v0 = up4(fb4[s0 * 32 + lane]);
            float4 v1 = up4(fb4[s1 * 32 + lane]);
            float4 v2 = up4(fb4[s2 * 32 + lane]);
            float4 v3 = up4(fb4[s3 * 32 + lane]);
            a0.x += v0.x; a0.y += v0.y; a0.z += v0.z; a0.w += v0.w;
            a1.x += v1.x; a1.y += v1.y; a1.z += v1.z; a1.w += v1.w;
            a2.x += v2.x; a2.y += v2.y; a2.z += v2.z; a2.w += v2.w;
            a3.x += v3.x; a3.y += v3.y; a3.z += v3.z; a3.w += v3.w;
        }
        for (; e < end; ++e) {
            float4 v0 = up4(fb4[e_src[e] * 32 + lane]);
            a0.x += v0.x; a0.y += v0.y; a0.z += v0.z; a0.w += v0.w;
        }
        float snd = nd[node];
        ushort4 h;
        h.x = bf16r((a0.x + a1.x + a2.x + a3.x) * snd);
        h.y = bf16r((a0.y + a1.y + a2.y + a3.y) * snd);
        h.z = bf16r((a0.z + a1.z + a2.z + a3.z) * snd);
        h.w = bf16r((a0.w + a1.w + a2.w + a3.w) * snd);
        ((ushort4*)(AsH + nl * 128))[lane] = h;
    }
    __syncthreads();

    const int rr = tid >> 5;  // rows rr*4 .. rr*4+3
    const int cc = tid & 31;  // cols cc*4 .. cc*4+3

    float accC[4][4] = {{0.f}};
    float accR[4][4] = {{0.f}};

    for (int k4 = 0; k4 < 32; ++k4) {
        float4 a4[4], f4[4];
#pragma unroll
        for (int r = 0; r < 4; ++r) {
            a4[r] = up4(((const ushort4*)(AsH + (rr * 4 + r) * 128))[k4]);
            f4[r] = up4(((const ushort4*)(FsH + (rr * 4 + r) * 128))[k4]);
        }
#pragma unroll
        for (int kk = 0; kk < 4; ++kk) {
            int k = k4 * 4 + kk;
            float4 wv = ((const float4*)W)[k * 32 + cc];
            float4 wrv = ((const float4*)Wr)[k * 32 + cc];
#pragma unroll
            for (int r = 0; r < 4; ++r) {
                float a = (kk == 0) ? a4[r].x : (kk == 1) ? a4[r].y : (kk == 2) ? a4[r].z : a4[r].w;
                float f = (kk == 0) ? f4[r].x : (kk == 1) ? f4[r].y : (kk == 2) ? f4[r].z : f4[r].w;
                accC[r][0] += a * wv.x;  accC[r][1] += a * wv.y;
                accC[r][2] += a * wv.z;  accC[r][3] += a * wv.w;
                accR[r][0] += f * wrv.x; accR[r][1] += f * wrv.y;
                accR[r][2] += f * wrv.z; accR[r][3] += f * wrv.w;
            }
        }
    }

    float4 bv = ((const float4*)b)[cc];
    float4 brv = ((const float4*)br)[cc];
    float csum[4] = {0.f, 0.f, 0.f, 0.f};
    float csq[4] = {0.f, 0.f, 0.f, 0.f};
#pragma unroll
    for (int r = 0; r < 4; ++r) {
        int row = block_row + rr * 4 + r;
        float4 o;
        o.x = fmaxf(accC[r][0] + bv.x, 0.f) + fmaxf(accR[r][0] + brv.x, 0.f);
        o.y = fmaxf(accC[r][1] + bv.y, 0.f) + fmaxf(accR[r][1] + brv.y, 0.f);
        o.z = fmaxf(accC[r][2] + bv.z, 0.f) + fmaxf(accR[r][2] + brv.z, 0.f);
        o.w = fmaxf(accC[r][3] + bv.w, 0.f) + fmaxf(accR[r][3] + brv.w, 0.f);
        ((float4*)y)[(size_t)row * 32 + cc] = o;
        csum[0] += o.x; csum[1] += o.y; csum[2] += o.z; csum[3] += o.w;
        csq[0] += o.x * o.x; csq[1] += o.y * o.y; csq[2] += o.z * o.z; csq[3] += o.w * o.w;
    }

    // block-level column reduction: reuse AsH (sum) and FsH (sumsq) as float arrays
    __syncthreads();
    float* Ssum = (float*)AsH;  // 2048 floats avail, need 1024
    float* Ssq = (float*)FsH;
#pragma unroll
    for (int j = 0; j < 4; ++j) {
        Ssum[rr * 128 + cc * 4 + j] = csum[j];
        Ssq[rr * 128 + cc * 4 + j] = csq[j];
    }
    __syncthreads();
    if (tid < 128) {
        float s = 0.f, q = 0.f;
#pragma unroll
        for (int g = 0; g < 8; ++g) {
            s += Ssum[g * 128 + tid];
            q += Ssq[g * 128 + tid];
        }
        atomicAdd(&colsum[tid], s);
        atomicAdd(&colsumsq[tid], q);
    }
}

// ---------------- BN stats finalize ----------------
__global__ void stats_kernel(const float* __restrict__ colsum, const float* __restrict__ colsumsq,
                             const float* __restrict__ gamma, const float* __restrict__ beta,
                             float* __restrict__ scale, float* __restrict__ shift) {
    int j = threadIdx.x;
    if (j < DD) {
        float inv_n = 1.0f / (float)NN;
        float mean = colsum[j] * inv_n;
        float var = colsumsq[j] * inv_n - mean * mean;
        float sc = gamma[j] * rsqrtf(var + BN_EPS);
        scale[j] = sc;
        shift[j] = beta[j] - mean * sc;
    }
}

// ---------------- BN apply (in place on d_out) ----------------
__global__ void apply_kernel(float4* __restrict__ y4,
                             const float* __restrict__ scale, const float* __restrict__ shift,
                             int total4) {
    int i = blockIdx.x * blockDim.x + threadIdx.x;
    if (i < total4) {
        int c4 = i & 31;
        float4 v = y4[i];
        float4 sc = ((const float4*)scale)[c4];
        float4 sh = ((const float4*)shift)[c4];
        v.x = v.x * sc.x + sh.x;
        v.y = v.y * sc.y + sh.y;
        v.z = v.z * sc.z + sh.z;
        v.w = v.w * sc.w + sh.w;
        y4[i] = v;
    }
}

extern "C" void kernel_launch(void* const* d_in, const int* in_sizes, int n_in,
                              void* d_out, int out_size, void* d_ws, size_t ws_size,
                              hipStream_t stream) {
    const float* feats = (const float*)d_in[0];
    const int* src = (const int*)d_in[1];
    const int* dst = (const int*)d_in[2];
    const float* W = (const float*)d_in[3];
    const float* b = (const float*)d_in[4];
    const float* Wr = (const float*)d_in[5];
    const float* br = (const float*)d_in[6];
    const float* gamma = (const float*)d_in[7];
    const float* beta = (const float*)d_in[8];
    float* y = (float*)d_out;

    // workspace carve
    char* ws = (char*)d_ws;
    ushort4* fb4 = (ushort4*)ws;                              // NN*32 ushort4 = 25.6 MB
    int* outdeg = (int*)(ws + (size_t)NN * 32 * 8);           // NN
    int* indeg = outdeg + NN;                                 // NN
    float* ns = (float*)(indeg + NN);                         // NN
    float* nd = ns + NN;                                      // NN
    int* row_ofs = (int*)(nd + NN);                           // NN+1
    int* cursor = row_ofs + NN + 1;                           // NN
    int* partial = cursor + NN;                               // NN
    int* blocksum = partial + NN;                             // 98
    int* blockofs = blocksum + 128;                           // 98
    int* e_src = blockofs + 128;                              // EE
    float* colsum = (float*)(e_src + EE);                     // 128
    float* colsumsq = colsum + DD;                            // 128
    float* scale = colsumsq + DD;                             // 128
    float* shift = scale + DD;                                // 128

    hipMemsetAsync(outdeg, 0, 2 * (size_t)NN * sizeof(int), stream);
    hipMemsetAsync(colsum, 0, 2 * (size_t)DD * sizeof(float), stream);

    deg4_kernel<<<(EE / 4 + 255) / 256, 256, 0, stream>>>((const int4*)src, (const int4*)dst,
                                                          outdeg, indeg);
    scan1_kernel<<<98, 1024, 0, stream>>>(indeg, partial, blocksum);
    scan2_kernel<<<1, 128, 0, stream>>>(blocksum, blockofs);
    scan3_kernel<<<(NN + 255) / 256, 256, 0, stream>>>(partial, blockofs, outdeg, indeg,
                                                       row_ofs, cursor, ns, nd);
    cvt_kernel<<<(NN * 32 + 255) / 256, 256, 0, stream>>>((const float4*)feats, ns, fb4);
    fill4_kernel<<<(EE / 4 + 255) / 256, 256, 0, stream>>>((const int4*)src, (const int4*)dst,
                                                           cursor, e_src);
    gg_kernel<<<NN / 32, 256, 0, stream>>>(feats, fb4, nd, row_ofs, e_src,
                                           W, b, Wr, br, y, colsum, colsumsq);
    stats_kernel<<<1, 128, 0, stream>>>(colsum, colsumsq, gamma, beta, scale, shift);
    {
        int total4 = NN * DD / 4;
        apply_kernel<<<(total4 + 255) / 256, 256, 0, stream>>>((float4*)y, scale, shift, total4);
    }
}